// Round 9
// baseline (498.147 us; speedup 1.0000x reference)
//
#include <hip/hip_runtime.h>
#include <math.h>

// Problem constants
#define B_   4
#define S_   2048
#define D_   1024
#define H_   1024
#define NROW 2048
#define TOTX 8388608.0f            // B_*S_*D_ elements of x

typedef _Float16 f16x8 __attribute__((ext_vector_type(8)));
typedef float f32x4 __attribute__((ext_vector_type(4)));

__device__ __forceinline__ unsigned short f2h(float f) {
  _Float16 h = (_Float16)f;                       // v_cvt_f16_f32, RNE
  return __builtin_bit_cast(unsigned short, h);
}

// async global->LDS, 16B per lane, lands at ldsbase + lane*16
#define GLD16(gp, lp)                                                            \
  __builtin_amdgcn_global_load_lds(                                              \
      (__attribute__((address_space(1))) void*)(gp),                             \
      (__attribute__((address_space(3))) void*)(lp), 16, 0, 0)

// ---------------------------------------------------------------------------
// prep: abs-sum(x) + f2h(x) fused single pass, plus f2h of Wq/Wk/Wv.
// Block ranges: [0,8192) -> x; [8192,9216) Wq; [9216,10240) Wk; [10240,11264) Wv
// ---------------------------------------------------------------------------
__global__ __launch_bounds__(256) void prep_kernel(const float* __restrict__ x,
                                                   const float* __restrict__ Wq,
                                                   const float* __restrict__ Wk,
                                                   const float* __restrict__ Wv,
                                                   unsigned short* __restrict__ x16,
                                                   unsigned short* __restrict__ Wq16,
                                                   unsigned short* __restrict__ Wk16,
                                                   unsigned short* __restrict__ Wv16,
                                                   float* __restrict__ flag) {
  const int b = blockIdx.x;
  const int t = threadIdx.x;
  if (b < 8192) {
    const int i = b * 256 + t;
    float4 v = ((const float4*)x)[i];
    ushort4 o;
    o.x = f2h(v.x); o.y = f2h(v.y); o.z = f2h(v.z); o.w = f2h(v.w);
    ((ushort4*)x16)[i] = o;
    float s = fabsf(v.x) + fabsf(v.y) + fabsf(v.z) + fabsf(v.w);
#pragma unroll
    for (int off = 32; off; off >>= 1) s += __shfl_xor(s, off);
    __shared__ float red[4];
    if ((t & 63) == 0) red[t >> 6] = s;
    __syncthreads();
    if (t == 0) atomicAdd(flag, red[0] + red[1] + red[2] + red[3]);
  } else {
    const float* src;
    unsigned short* dst;
    int i;
    if (b < 9216)       { src = Wq; dst = Wq16; i = (b - 8192) * 256 + t; }
    else if (b < 10240) { src = Wk; dst = Wk16; i = (b - 9216) * 256 + t; }
    else                { src = Wv; dst = Wv16; i = (b - 10240) * 256 + t; }
    float4 v = ((const float4*)src)[i];
    ushort4 o;
    o.x = f2h(v.x); o.y = f2h(v.y); o.z = f2h(v.z); o.w = f2h(v.w);
    ((ushort4*)dst)[i] = o;
  }
}

// ---------------------------------------------------------------------------
// 16-bit transpose per batch: in [R][C] -> out [C][R]
// ---------------------------------------------------------------------------
__global__ __launch_bounds__(256) void transpose_h16(const unsigned short* __restrict__ in,
                                                     unsigned short* __restrict__ out,
                                                     int R, int C) {
  __shared__ unsigned short t[32][33];
  const int z = blockIdx.z;
  in  += (long long)z * R * C;
  out += (long long)z * R * C;
  const int c0 = blockIdx.x * 32, r0 = blockIdx.y * 32;
#pragma unroll
  for (int i = 0; i < 4; ++i) {
    int r = threadIdx.y + i * 8;
    t[r][threadIdx.x] = in[(long long)(r0 + r) * C + c0 + threadIdx.x];
  }
  __syncthreads();
#pragma unroll
  for (int i = 0; i < 4; ++i) {
    int r = threadIdx.y + i * 8;
    out[(long long)(c0 + r) * R + r0 + threadIdx.x] = t[threadIdx.x][r];
  }
}

// ---------------------------------------------------------------------------
// f16 MFMA GEMM NT core (m97 structure): C[m,n] = scale * sum_k A[m,k]*B[n,k]
// 128x128 tile, BK=32, 256 thr (4 waves), 4x4 16x16x32 MFMAs per wave.
// Staging: global_load_lds 16B/lane into LINEAR LDS with XOR chunk swizzle
// (chunk ^= (row>>1)&3) so ds_read_b128 fragment reads are 2-way (free).
// ---------------------------------------------------------------------------
template <bool OUT_F16>
__device__ __forceinline__ void gemm_nt_core(const unsigned short* __restrict__ A,
                                             const unsigned short* __restrict__ B,
                                             void* __restrict__ Cv,  // batch-offset applied
                                             int N, int K, float scale) {
  __shared__ __align__(16) unsigned short As[128 * 32];   // linear, 64B row stride
  __shared__ __align__(16) unsigned short Bs[128 * 32];

  const int tid = threadIdx.x;
  const int lane = tid & 63;
  const int w = tid >> 6;
  const int wm = (w & 1) << 6;
  const int wn = (w >> 1) << 6;
  const int m0 = blockIdx.y * 128, n0 = blockIdx.x * 128;

  f32x4 acc[4][4] = {};

  // staging: lane l of wave w fetches row (w*16 + l/4), global chunk c = (l&3)^((l>>3)&3)
  const int srow = tid >> 2;                               // = w*16 + (lane>>2)
  const int scol = ((lane & 3) ^ ((lane >> 3) & 3)) * 8;   // f16 elems
  unsigned short* aL0 = &As[(w * 16) * 32];
  unsigned short* aL1 = &As[(64 + w * 16) * 32];
  unsigned short* bL0 = &Bs[(w * 16) * 32];
  unsigned short* bL1 = &Bs[(64 + w * 16) * 32];

  // fragment read addresses (loop-invariant)
  const int fm = lane & 15;
  const int col8 = (((lane >> 4) ^ ((lane >> 1) & 3)) * 8);
  const unsigned short* afp[4];
  const unsigned short* bfp[4];
#pragma unroll
  for (int mi = 0; mi < 4; ++mi) {
    afp[mi] = &As[(wm + mi * 16 + fm) * 32 + col8];
    bfp[mi] = &Bs[(wn + mi * 16 + fm) * 32 + col8];
  }

  const unsigned short* gA0 = A + (long long)(m0 + srow) * K + scol;
  const unsigned short* gA1 = A + (long long)(m0 + 64 + srow) * K + scol;
  const unsigned short* gB0 = B + (long long)(n0 + srow) * K + scol;
  const unsigned short* gB1 = B + (long long)(n0 + 64 + srow) * K + scol;

  for (int k0 = 0; k0 < K; k0 += 32) {
    GLD16(gA0 + k0, aL0);
    GLD16(gA1 + k0, aL1);
    GLD16(gB0 + k0, bL0);
    GLD16(gB1 + k0, bL1);
    __syncthreads();

    f16x8 af[4], bfr[4];
#pragma unroll
    for (int mi = 0; mi < 4; ++mi) af[mi] = *(const f16x8*)afp[mi];
#pragma unroll
    for (int ni = 0; ni < 4; ++ni) bfr[ni] = *(const f16x8*)bfp[ni];
#pragma unroll
    for (int mi = 0; mi < 4; ++mi)
#pragma unroll
      for (int ni = 0; ni < 4; ++ni)
        acc[mi][ni] = __builtin_amdgcn_mfma_f32_16x16x32_f16(af[mi], bfr[ni],
                                                             acc[mi][ni], 0, 0, 0);
    __syncthreads();
  }

  // epilogue: C/D layout col=lane&15, row=(lane>>4)*4+reg
  const int cm = (lane >> 4) * 4;
  const int cn = lane & 15;
#pragma unroll
  for (int mi = 0; mi < 4; ++mi)
#pragma unroll
    for (int ni = 0; ni < 4; ++ni) {
#pragma unroll
      for (int r = 0; r < 4; ++r) {
        long long m = m0 + wm + mi * 16 + cm + r;
        long long n = n0 + wn + ni * 16 + cn;
        float v = acc[mi][ni][r] * scale;
        if (OUT_F16)
          ((unsigned short*)Cv)[m * N + n] = f2h(v);
        else
          ((float*)Cv)[m * N + n] = v;
      }
    }
}

template <bool OUT_F16>
__global__ __launch_bounds__(256) void gemm_nt_mfma(const unsigned short* __restrict__ A,
                                                    const unsigned short* __restrict__ B,
                                                    void* __restrict__ Cv,
                                                    int N, int K,
                                                    long long sA, long long sB, long long sC,
                                                    float scale) {
  const int bz = blockIdx.z;
  char* Cp = (char*)Cv + (long long)bz * sC * (OUT_F16 ? 2 : 4);
  gemm_nt_core<OUT_F16>(A + (long long)bz * sA, B + (long long)bz * sB, Cp, N, K, scale);
}

// merged Q/K/V projections: blockIdx.z selects weight/output
__global__ __launch_bounds__(256) void proj3(const unsigned short* __restrict__ x16,
                                             const unsigned short* __restrict__ W0,
                                             const unsigned short* __restrict__ W1,
                                             const unsigned short* __restrict__ W2,
                                             unsigned short* __restrict__ O0,
                                             unsigned short* __restrict__ O1,
                                             unsigned short* __restrict__ O2) {
  const int z = blockIdx.z;
  const unsigned short* B = (z == 0) ? W0 : (z == 1) ? W1 : W2;
  unsigned short* C = (z == 0) ? O0 : (z == 1) ? O1 : O2;
  gemm_nt_core<true>(x16, B, C, H_, D_, 1.0f);
}

// ---------------------------------------------------------------------------
// Wave-per-row sparsemax/softmax. Element e = lane*32 + v, 32 values/lane in
// VGPRs. Register bitonic; no LDS, no __syncthreads. f16 output.
// ---------------------------------------------------------------------------
template <int K, int J>
__device__ __forceinline__ void intra_s(float (&r)[32]) {
#pragma unroll
  for (int v = 0; v < 32; ++v)
    if ((v & J) == 0) {
      const int u = v | J;
      const bool dsc = ((v & K) == 0);
      float a = r[v], b = r[u];
      float mx = fmaxf(a, b), mn = fminf(a, b);
      r[v] = dsc ? mx : mn;
      r[u] = dsc ? mn : mx;
    }
}
template <int J>
__device__ __forceinline__ void intra_d(float (&r)[32], bool dsc) {
#pragma unroll
  for (int v = 0; v < 32; ++v)
    if ((v & J) == 0) {
      const int u = v | J;
      float a = r[v], b = r[u];
      float mx = fmaxf(a, b), mn = fminf(a, b);
      r[v] = dsc ? mx : mn;
      r[u] = dsc ? mn : mx;
    }
}
__device__ __forceinline__ void cross_s(float (&r)[32], int lane, int jl, bool dsc) {
  const bool lower = ((lane & jl) == 0);
  const bool tmax = (dsc == lower);
#pragma unroll
  for (int v = 0; v < 32; ++v) {
    float a = r[v];
    float b = __shfl_xor(a, jl, 64);
    float mx = fmaxf(a, b), mn = fminf(a, b);
    r[v] = tmax ? mx : mn;
  }
}

__global__ __launch_bounds__(256) void attn_row_wave(const float* __restrict__ scores,
                                                     unsigned short* __restrict__ attn,
                                                     const float* __restrict__ absSum) {
  const int tid = threadIdx.x;
  const int lane = tid & 63;
  const int row = blockIdx.x * 4 + (tid >> 6);
  const float* rowp = scores + (long long)row * NROW;
  unsigned short* aout = attn + (long long)row * NROW;

  float z[32];
  const float4* rp4 = (const float4*)(rowp + lane * 32);
#pragma unroll
  for (int q = 0; q < 8; ++q) {
    float4 v4 = rp4[q];
    z[q * 4 + 0] = v4.x; z[q * 4 + 1] = v4.y;
    z[q * 4 + 2] = v4.z; z[q * 4 + 3] = v4.w;
  }

  // row max (wave reduce)
  float lm = z[0];
#pragma unroll
  for (int v = 1; v < 32; ++v) lm = fmaxf(lm, z[v]);
#pragma unroll
  for (int off = 32; off; off >>= 1) lm = fmaxf(lm, __shfl_xor(lm, off, 64));

  const bool use_softmax = (absSum[0] * (1.0f / TOTX)) >= 1.0f;

  if (use_softmax) {
    float ls = 0.f;
#pragma unroll
    for (int v = 0; v < 32; ++v) { z[v] = expf(z[v] - lm); ls += z[v]; }
#pragma unroll
    for (int off = 32; off; off >>= 1) ls += __shfl_xor(ls, off, 64);
    float inv = 1.0f / ls;
    ushort4* op = (ushort4*)(aout + lane * 32);
#pragma unroll
    for (int q = 0; q < 8; ++q) {
      ushort4 o;
      o.x = f2h(z[q * 4 + 0] * inv); o.y = f2h(z[q * 4 + 1] * inv);
      o.z = f2h(z[q * 4 + 2] * inv); o.w = f2h(z[q * 4 + 3] * inv);
      op[q] = o;
    }
    return;
  }

  // ---- sparsemax ----
  float r[32];
  float lsum = 0.f;
#pragma unroll
  for (int v = 0; v < 32; ++v) { z[v] -= lm; r[v] = z[v]; lsum += z[v]; }
#pragma unroll
  for (int off = 32; off; off >>= 1) lsum += __shfl_xor(lsum, off, 64);
  const float step = (lsum - 1.0f) * (1.0f / (float)NROW);

  // bitonic sort descending, e = lane*32 + v
  intra_s<2, 1>(r);
  intra_s<4, 2>(r); intra_s<4, 1>(r);
  intra_s<8, 4>(r); intra_s<8, 2>(r); intra_s<8, 1>(r);
  intra_s<16, 8>(r); intra_s<16, 4>(r); intra_s<16, 2>(r); intra_s<16, 1>(r);
  for (int kl = 1; kl <= 64; kl <<= 1) {
    const bool dsc = ((lane & kl) == 0);
    for (int jl = kl >> 1; jl >= 1; jl >>= 1) cross_s(r, lane, jl, dsc);
    intra_d<16>(r, dsc); intra_d<8>(r, dsc); intra_d<4>(r, dsc);
    intra_d<2>(r, dsc); intra_d<1>(r, dsc);
  }

  // k = count(sorted > step)
  float lcnt = 0.f;
#pragma unroll
  for (int v = 0; v < 32; ++v) lcnt += (r[v] > step) ? 1.0f : 0.0f;
#pragma unroll
  for (int off = 32; off; off >>= 1) lcnt += __shfl_xor(lcnt, off, 64);
  const float kf = lcnt;

  // inclusive cumsum over e: local sequential + wave scan of lane totals
  float run = 0.f;
#pragma unroll
  for (int v = 0; v < 32; ++v) { run += r[v]; r[v] = run; }
  float pre = run;
#pragma unroll
  for (int off = 1; off < 64; off <<= 1) {
    float t = __shfl_up(pre, off, 64);
    if (lane >= off) pre += t;
  }
  pre -= run;  // exclusive prefix of lane totals
#pragma unroll
  for (int v = 0; v < 32; ++v) r[v] += pre;

  const float inv_k = 1.0f / kf;
  const float c1 = 1.0f + step * kf;
  ushort4* op = (ushort4*)(aout + lane * 32);
#pragma unroll
  for (int q = 0; q < 8; ++q) {
    ushort4 o;
    o.x = f2h(fmaxf(z[q * 4 + 0] - (r[q * 4 + 0] - c1) * inv_k, 0.0f));
    o.y = f2h(fmaxf(z[q * 4 + 1] - (r[q * 4 + 1] - c1) * inv_k, 0.0f));
    o.z = f2h(fmaxf(z[q * 4 + 2] - (r[q * 4 + 2] - c1) * inv_k, 0.0f));
    o.w = f2h(fmaxf(z[q * 4 + 3] - (r[q * 4 + 3] - c1) * inv_k, 0.0f));
    op[q] = o;
  }
}

// ---------------------------------------------------------------------------
extern "C" void kernel_launch(void* const* d_in, const int* in_sizes, int n_in,
                              void* d_out, int out_size, void* d_ws, size_t ws_size,
                              hipStream_t stream) {
  const float* x  = (const float*)d_in[0];
  const float* Wq = (const float*)d_in[1];
  const float* Wk = (const float*)d_in[2];
  const float* Wv = (const float*)d_in[3];
  float* out = (float*)d_out;

  // Workspace layout with aliasing (total 144 MB + 4 B):
  //  [0,64MB):    x16(16) Wq16(2) Wk16(2) Wv16(2) V16(16) slack -> later Sc (fp32, 64MB)
  //  [64,80MB):   Vt16 (16MB, persists to PV)
  //  [80,96MB):   Q16 (16MB)   [96,112MB): K16 (16MB)
  //  [112,144MB): A16 (f16 attention, 32MB)
  //  [144MB]:     flag
  char* base = (char*)d_ws;
  unsigned short* x16  = (unsigned short*)(base);
  unsigned short* Wq16 = (unsigned short*)(base + (16ll << 20));
  unsigned short* Wk16 = (unsigned short*)(base + (18ll << 20));
  unsigned short* Wv16 = (unsigned short*)(base + (20ll << 20));
  unsigned short* V16  = (unsigned short*)(base + (22ll << 20));
  float*          Sc   = (float*)(base);
  unsigned short* Vt16 = (unsigned short*)(base + (64ll << 20));
  unsigned short* Q16  = (unsigned short*)(base + (80ll << 20));
  unsigned short* K16  = (unsigned short*)(base + (96ll << 20));
  unsigned short* A16  = (unsigned short*)(base + (112ll << 20));
  float*          flag = (float*)(base + (144ll << 20));

  hipMemsetAsync(flag, 0, sizeof(float), stream);

  // prep: abs-sum + all f16 conversions (one pass over x)
  prep_kernel<<<11264, 256, 0, stream>>>(x, Wq, Wk, Wv, x16, Wq16, Wk16, Wv16, flag);

  // Projections: Q/K/V = x @ W^T  (M=8192, N=1024, K=1024), f16 out, one dispatch
  {
    dim3 grid(H_ / 128, (B_ * S_) / 128, 3);
    proj3<<<grid, 256, 0, stream>>>(x16, Wq16, Wk16, Wv16, Q16, K16, V16);
  }

  // V^T per batch: [S][H] -> [H][S]
  {
    dim3 grid(H_ / 32, S_ / 32, B_);
    transpose_h16<<<grid, dim3(32, 8), 0, stream>>>(V16, Vt16, S_, H_);
  }

  // scores = Q @ K^T / 32 (batched, fp32 out; N=S_, K=H_)
  {
    dim3 grid(S_ / 128, S_ / 128, B_);
    gemm_nt_mfma<false><<<grid, 256, 0, stream>>>(Q16, K16, Sc, S_, H_,
                                                  (long long)S_ * H_, (long long)S_ * H_,
                                                  (long long)S_ * S_, 1.0f / 32.0f);
  }

  // attention = sparsemax-or-softmax(scores) -> f16 (one wave per row)
  attn_row_wave<<<(B_ * S_) / 4, 256, 0, stream>>>(Sc, A16, flag);

  // out = attention @ Vt^T, f16 MFMA, fp32 out (N=H_, K=S_)
  {
    dim3 grid(H_ / 128, S_ / 128, B_);
    gemm_nt_mfma<false><<<grid, 256, 0, stream>>>(A16, Vt16, out, H_, S_,
                                                  (long long)S_ * S_, (long long)H_ * S_,
                                                  (long long)S_ * H_, 1.0f);
  }
}

// Round 10
// 440.226 us; speedup vs baseline: 1.1316x; 1.1316x over previous
//
#include <hip/hip_runtime.h>
#include <math.h>

// Problem constants
#define B_   4
#define S_   2048
#define D_   1024
#define H_   1024
#define NROW 2048
#define TOTX 8388608.0f            // B_*S_*D_ elements of x

typedef _Float16 f16x8 __attribute__((ext_vector_type(8)));
typedef float f32x4 __attribute__((ext_vector_type(4)));

__device__ __forceinline__ unsigned short f2h(float f) {
  _Float16 h = (_Float16)f;                       // v_cvt_f16_f32, RNE
  return __builtin_bit_cast(unsigned short, h);
}

// async global->LDS, 16B per lane, lands at ldsbase + lane*16
#define GLD16(gp, lp)                                                            \
  __builtin_amdgcn_global_load_lds(                                              \
      (__attribute__((address_space(1))) void*)(gp),                             \
      (__attribute__((address_space(3))) void*)(lp), 16, 0, 0)

// ---------------------------------------------------------------------------
// abs-sum reduction for sparsity = mean(|x|)
// ---------------------------------------------------------------------------
__global__ __launch_bounds__(256) void abs_sum_kernel(const float* __restrict__ x,
                                                      long long n4, float* out) {
  long long i0 = (long long)blockIdx.x * blockDim.x + threadIdx.x;
  long long stride = (long long)gridDim.x * blockDim.x;
  float s = 0.f;
  const float4* x4 = (const float4*)x;
  for (long long i = i0; i < n4; i += stride) {
    float4 v = x4[i];
    s += fabsf(v.x) + fabsf(v.y) + fabsf(v.z) + fabsf(v.w);
  }
#pragma unroll
  for (int off = 32; off; off >>= 1) s += __shfl_xor(s, off);
  __shared__ float red[4];
  if ((threadIdx.x & 63) == 0) red[threadIdx.x >> 6] = s;
  __syncthreads();
  if (threadIdx.x == 0) atomicAdd(out, red[0] + red[1] + red[2] + red[3]);
}

// ---------------------------------------------------------------------------
// float -> f16 (bit pattern in ushort), vectorized
// ---------------------------------------------------------------------------
__global__ __launch_bounds__(256) void f2h_kernel(const float* __restrict__ in,
                                                  unsigned short* __restrict__ out,
                                                  int n4) {
  int i = blockIdx.x * 256 + threadIdx.x;
  if (i >= n4) return;
  float4 v = ((const float4*)in)[i];
  ushort4 o;
  o.x = f2h(v.x); o.y = f2h(v.y); o.z = f2h(v.z); o.w = f2h(v.w);
  ((ushort4*)out)[i] = o;
}

// ---------------------------------------------------------------------------
// 16-bit transpose per batch: in [R][C] -> out [C][R]
// ---------------------------------------------------------------------------
__global__ __launch_bounds__(256) void transpose_h16(const unsigned short* __restrict__ in,
                                                     unsigned short* __restrict__ out,
                                                     int R, int C) {
  __shared__ unsigned short t[32][33];
  const int z = blockIdx.z;
  in  += (long long)z * R * C;
  out += (long long)z * R * C;
  const int c0 = blockIdx.x * 32, r0 = blockIdx.y * 32;
#pragma unroll
  for (int i = 0; i < 4; ++i) {
    int r = threadIdx.y + i * 8;
    t[r][threadIdx.x] = in[(long long)(r0 + r) * C + c0 + threadIdx.x];
  }
  __syncthreads();
#pragma unroll
  for (int i = 0; i < 4; ++i) {
    int r = threadIdx.y + i * 8;
    out[(long long)(c0 + r) * R + r0 + threadIdx.x] = t[threadIdx.x][r];
  }
}

// ---------------------------------------------------------------------------
// f16 MFMA GEMM NT (m97 structure): C[m,n] = scale * sum_k A[m,k]*B[n,k]
// 128x128 tile, BK=32, 256 thr (4 waves), 4x4 16x16x32 MFMAs per wave.
// Staging: global_load_lds 16B/lane into LINEAR LDS with XOR chunk swizzle
// (chunk ^= (row>>1)&3) so ds_read_b128 fragment reads are 2-way (free).
// ---------------------------------------------------------------------------
template <bool OUT_F16>
__global__ __launch_bounds__(256) void gemm_nt_mfma(const unsigned short* __restrict__ A,
                                                    const unsigned short* __restrict__ B,
                                                    void* __restrict__ Cv,
                                                    int M, int N, int K,
                                                    long long sA, long long sB, long long sC,
                                                    float scale) {
  const int bz = blockIdx.z;
  A += (long long)bz * sA;
  B += (long long)bz * sB;

  __shared__ __align__(16) unsigned short As[128 * 32];   // linear, 64B row stride
  __shared__ __align__(16) unsigned short Bs[128 * 32];

  const int tid = threadIdx.x;
  const int lane = tid & 63;
  const int w = tid >> 6;
  const int wm = (w & 1) << 6;
  const int wn = (w >> 1) << 6;
  const int m0 = blockIdx.y * 128, n0 = blockIdx.x * 128;

  f32x4 acc[4][4] = {};

  // staging: lane l of wave w fetches row (w*16 + l/4), global chunk c = (l&3)^((l>>3)&3)
  const int srow = tid >> 2;                               // = w*16 + (lane>>2)
  const int scol = ((lane & 3) ^ ((lane >> 3) & 3)) * 8;   // f16 elems
  unsigned short* aL0 = &As[(w * 16) * 32];
  unsigned short* aL1 = &As[(64 + w * 16) * 32];
  unsigned short* bL0 = &Bs[(w * 16) * 32];
  unsigned short* bL1 = &Bs[(64 + w * 16) * 32];

  // fragment read addresses (loop-invariant)
  const int fm = lane & 15;
  const int col8 = (((lane >> 4) ^ ((lane >> 1) & 3)) * 8);
  const unsigned short* afp[4];
  const unsigned short* bfp[4];
#pragma unroll
  for (int mi = 0; mi < 4; ++mi) {
    afp[mi] = &As[(wm + mi * 16 + fm) * 32 + col8];
    bfp[mi] = &Bs[(wn + mi * 16 + fm) * 32 + col8];
  }

  const unsigned short* gA0 = A + (long long)(m0 + srow) * K + scol;
  const unsigned short* gA1 = A + (long long)(m0 + 64 + srow) * K + scol;
  const unsigned short* gB0 = B + (long long)(n0 + srow) * K + scol;
  const unsigned short* gB1 = B + (long long)(n0 + 64 + srow) * K + scol;

  for (int k0 = 0; k0 < K; k0 += 32) {
    GLD16(gA0 + k0, aL0);
    GLD16(gA1 + k0, aL1);
    GLD16(gB0 + k0, bL0);
    GLD16(gB1 + k0, bL1);
    __syncthreads();

    f16x8 af[4], bfr[4];
#pragma unroll
    for (int mi = 0; mi < 4; ++mi) af[mi] = *(const f16x8*)afp[mi];
#pragma unroll
    for (int ni = 0; ni < 4; ++ni) bfr[ni] = *(const f16x8*)bfp[ni];
#pragma unroll
    for (int mi = 0; mi < 4; ++mi)
#pragma unroll
      for (int ni = 0; ni < 4; ++ni)
        acc[mi][ni] = __builtin_amdgcn_mfma_f32_16x16x32_f16(af[mi], bfr[ni],
                                                             acc[mi][ni], 0, 0, 0);
    __syncthreads();
  }

  // epilogue: C/D layout col=lane&15, row=(lane>>4)*4+reg
  const int cm = (lane >> 4) * 4;
  const int cn = lane & 15;
#pragma unroll
  for (int mi = 0; mi < 4; ++mi)
#pragma unroll
    for (int ni = 0; ni < 4; ++ni) {
#pragma unroll
      for (int r = 0; r < 4; ++r) {
        long long m = m0 + wm + mi * 16 + cm + r;
        long long n = n0 + wn + ni * 16 + cn;
        float v = acc[mi][ni][r] * scale;
        if (OUT_F16)
          ((unsigned short*)Cv)[(long long)bz * sC + m * N + n] = f2h(v);
        else
          ((float*)Cv)[(long long)bz * sC + m * N + n] = v;
      }
    }
}

// ---------------------------------------------------------------------------
// Wave-per-row sparsemax/softmax. Element e = lane*32 + v, 32 values/lane in
// VGPRs. Register bitonic; no LDS, no __syncthreads. f16 output.
// __launch_bounds__(256, 1): grid only supplies 2 waves/SIMD, so allow the
// allocator a full VGPR budget (z[32]+r[32] live) — avoids scratch spills.
// ---------------------------------------------------------------------------
template <int K, int J>
__device__ __forceinline__ void intra_s(float (&r)[32]) {
#pragma unroll
  for (int v = 0; v < 32; ++v)
    if ((v & J) == 0) {
      const int u = v | J;
      const bool dsc = ((v & K) == 0);
      float a = r[v], b = r[u];
      float mx = fmaxf(a, b), mn = fminf(a, b);
      r[v] = dsc ? mx : mn;
      r[u] = dsc ? mn : mx;
    }
}
template <int J>
__device__ __forceinline__ void intra_d(float (&r)[32], bool dsc) {
#pragma unroll
  for (int v = 0; v < 32; ++v)
    if ((v & J) == 0) {
      const int u = v | J;
      float a = r[v], b = r[u];
      float mx = fmaxf(a, b), mn = fminf(a, b);
      r[v] = dsc ? mx : mn;
      r[u] = dsc ? mn : mx;
    }
}
__device__ __forceinline__ void cross_s(float (&r)[32], int lane, int jl, bool dsc) {
  const bool lower = ((lane & jl) == 0);
  const bool tmax = (dsc == lower);
#pragma unroll
  for (int v = 0; v < 32; ++v) {
    float a = r[v];
    float b = __shfl_xor(a, jl, 64);
    float mx = fmaxf(a, b), mn = fminf(a, b);
    r[v] = tmax ? mx : mn;
  }
}

__global__ __launch_bounds__(256, 1) void attn_row_wave(const float* __restrict__ scores,
                                                        unsigned short* __restrict__ attn,
                                                        const float* __restrict__ absSum) {
  const int tid = threadIdx.x;
  const int lane = tid & 63;
  const int row = blockIdx.x * 4 + (tid >> 6);
  const float* rowp = scores + (long long)row * NROW;
  unsigned short* aout = attn + (long long)row * NROW;

  float z[32];
  const float4* rp4 = (const float4*)(rowp + lane * 32);
#pragma unroll
  for (int q = 0; q < 8; ++q) {
    float4 v4 = rp4[q];
    z[q * 4 + 0] = v4.x; z[q * 4 + 1] = v4.y;
    z[q * 4 + 2] = v4.z; z[q * 4 + 3] = v4.w;
  }

  // row max (wave reduce)
  float lm = z[0];
#pragma unroll
  for (int v = 1; v < 32; ++v) lm = fmaxf(lm, z[v]);
#pragma unroll
  for (int off = 32; off; off >>= 1) lm = fmaxf(lm, __shfl_xor(lm, off, 64));

  const bool use_softmax = (absSum[0] * (1.0f / TOTX)) >= 1.0f;

  if (use_softmax) {
    float ls = 0.f;
#pragma unroll
    for (int v = 0; v < 32; ++v) { z[v] = expf(z[v] - lm); ls += z[v]; }
#pragma unroll
    for (int off = 32; off; off >>= 1) ls += __shfl_xor(ls, off, 64);
    float inv = 1.0f / ls;
    ushort4* op = (ushort4*)(aout + lane * 32);
#pragma unroll
    for (int q = 0; q < 8; ++q) {
      ushort4 o;
      o.x = f2h(z[q * 4 + 0] * inv); o.y = f2h(z[q * 4 + 1] * inv);
      o.z = f2h(z[q * 4 + 2] * inv); o.w = f2h(z[q * 4 + 3] * inv);
      op[q] = o;
    }
    return;
  }

  // ---- sparsemax ----
  float r[32];
  float lsum = 0.f;
#pragma unroll
  for (int v = 0; v < 32; ++v) { z[v] -= lm; r[v] = z[v]; lsum += z[v]; }
#pragma unroll
  for (int off = 32; off; off >>= 1) lsum += __shfl_xor(lsum, off, 64);
  const float step = (lsum - 1.0f) * (1.0f / (float)NROW);

  // bitonic sort descending, e = lane*32 + v
  intra_s<2, 1>(r);
  intra_s<4, 2>(r); intra_s<4, 1>(r);
  intra_s<8, 4>(r); intra_s<8, 2>(r); intra_s<8, 1>(r);
  intra_s<16, 8>(r); intra_s<16, 4>(r); intra_s<16, 2>(r); intra_s<16, 1>(r);
  for (int kl = 1; kl <= 64; kl <<= 1) {
    const bool dsc = ((lane & kl) == 0);
    for (int jl = kl >> 1; jl >= 1; jl >>= 1) cross_s(r, lane, jl, dsc);
    intra_d<16>(r, dsc); intra_d<8>(r, dsc); intra_d<4>(r, dsc);
    intra_d<2>(r, dsc); intra_d<1>(r, dsc);
  }

  // k = count(sorted > step)
  float lcnt = 0.f;
#pragma unroll
  for (int v = 0; v < 32; ++v) lcnt += (r[v] > step) ? 1.0f : 0.0f;
#pragma unroll
  for (int off = 32; off; off >>= 1) lcnt += __shfl_xor(lcnt, off, 64);
  const float kf = lcnt;

  // inclusive cumsum over e: local sequential + wave scan of lane totals
  float run = 0.f;
#pragma unroll
  for (int v = 0; v < 32; ++v) { run += r[v]; r[v] = run; }
  float pre = run;
#pragma unroll
  for (int off = 1; off < 64; off <<= 1) {
    float t = __shfl_up(pre, off, 64);
    if (lane >= off) pre += t;
  }
  pre -= run;  // exclusive prefix of lane totals
#pragma unroll
  for (int v = 0; v < 32; ++v) r[v] += pre;

  const float inv_k = 1.0f / kf;
  const float c1 = 1.0f + step * kf;
  ushort4* op = (ushort4*)(aout + lane * 32);
#pragma unroll
  for (int q = 0; q < 8; ++q) {
    ushort4 o;
    o.x = f2h(fmaxf(z[q * 4 + 0] - (r[q * 4 + 0] - c1) * inv_k, 0.0f));
    o.y = f2h(fmaxf(z[q * 4 + 1] - (r[q * 4 + 1] - c1) * inv_k, 0.0f));
    o.z = f2h(fmaxf(z[q * 4 + 2] - (r[q * 4 + 2] - c1) * inv_k, 0.0f));
    o.w = f2h(fmaxf(z[q * 4 + 3] - (r[q * 4 + 3] - c1) * inv_k, 0.0f));
    op[q] = o;
  }
}

// ---------------------------------------------------------------------------
extern "C" void kernel_launch(void* const* d_in, const int* in_sizes, int n_in,
                              void* d_out, int out_size, void* d_ws, size_t ws_size,
                              hipStream_t stream) {
  const float* x  = (const float*)d_in[0];
  const float* Wq = (const float*)d_in[1];
  const float* Wk = (const float*)d_in[2];
  const float* Wv = (const float*)d_in[3];
  float* out = (float*)d_out;

  const long long NX = (long long)B_ * S_ * D_;   // 8M
  const long long NW = (long long)H_ * D_;        // 1M

  // Workspace layout with aliasing (total 144 MB + 4 B):
  //  [0,64MB):    x16(16) Wq16(2) Wk16(2) Wv16(2) V16(16) slack -> later Sc (fp32, 64MB)
  //  [64,80MB):   Vt16 (16MB, persists to PV)
  //  [80,96MB):   Q16 (16MB)   [96,112MB): K16 (16MB)
  //  [112,144MB): A16 (f16 attention, 32MB)
  //  [144MB]:     flag
  char* base = (char*)d_ws;
  unsigned short* x16  = (unsigned short*)(base);
  unsigned short* Wq16 = (unsigned short*)(base + (16ll << 20));
  unsigned short* Wk16 = (unsigned short*)(base + (18ll << 20));
  unsigned short* Wv16 = (unsigned short*)(base + (20ll << 20));
  unsigned short* V16  = (unsigned short*)(base + (22ll << 20));
  float*          Sc   = (float*)(base);
  unsigned short* Vt16 = (unsigned short*)(base + (64ll << 20));
  unsigned short* Q16  = (unsigned short*)(base + (80ll << 20));
  unsigned short* K16  = (unsigned short*)(base + (96ll << 20));
  unsigned short* A16  = (unsigned short*)(base + (112ll << 20));
  float*          flag = (float*)(base + (144ll << 20));

  hipMemsetAsync(flag, 0, sizeof(float), stream);
  abs_sum_kernel<<<512, 256, 0, stream>>>(x, NX / 4, flag);

  // f16 conversions
  f2h_kernel<<<(int)(NX / 4 + 255) / 256, 256, 0, stream>>>(x, x16, (int)(NX / 4));
  f2h_kernel<<<(int)(NW / 4 + 255) / 256, 256, 0, stream>>>(Wq, Wq16, (int)(NW / 4));
  f2h_kernel<<<(int)(NW / 4 + 255) / 256, 256, 0, stream>>>(Wk, Wk16, (int)(NW / 4));
  f2h_kernel<<<(int)(NW / 4 + 255) / 256, 256, 0, stream>>>(Wv, Wv16, (int)(NW / 4));

  // Projections: Q/K/V = x @ W^T  (M=8192, N=1024, K=1024), f16 out
  {
    dim3 grid(H_ / 128, (B_ * S_) / 128, 1);
    gemm_nt_mfma<true><<<grid, 256, 0, stream>>>(x16, Wq16, Q16, B_ * S_, H_, D_, 0, 0, 0, 1.0f);
    gemm_nt_mfma<true><<<grid, 256, 0, stream>>>(x16, Wk16, K16, B_ * S_, H_, D_, 0, 0, 0, 1.0f);
    gemm_nt_mfma<true><<<grid, 256, 0, stream>>>(x16, Wv16, V16, B_ * S_, H_, D_, 0, 0, 0, 1.0f);
  }

  // V^T per batch: [S][H] -> [H][S]
  {
    dim3 grid(H_ / 32, S_ / 32, B_);
    transpose_h16<<<grid, dim3(32, 8), 0, stream>>>(V16, Vt16, S_, H_);
  }

  // scores = Q @ K^T / 32 (batched, fp32 out; overwrites x16/W/V16 — all dead)
  {
    dim3 grid(S_ / 128, S_ / 128, B_);
    gemm_nt_mfma<false><<<grid, 256, 0, stream>>>(Q16, K16, Sc, S_, S_, H_,
                                                  (long long)S_ * H_, (long long)S_ * H_,
                                                  (long long)S_ * S_, 1.0f / 32.0f);
  }

  // attention = sparsemax-or-softmax(scores) -> f16 (one wave per row)
  attn_row_wave<<<(B_ * S_) / 4, 256, 0, stream>>>(Sc, A16, flag);

  // out = attention @ Vt^T, f16 MFMA, fp32 out
  {
    dim3 grid(H_ / 128, S_ / 128, B_);
    gemm_nt_mfma<false><<<grid, 256, 0, stream>>>(A16, Vt16, out, S_, H_, S_,
                                                  (long long)S_ * S_, (long long)H_ * S_,
                                                  (long long)S_ * H_, 1.0f);
  }
}